// Round 10
// baseline (287.397 us; speedup 1.0000x reference)
//
#include <hip/hip_runtime.h>
#include <hip/hip_bf16.h>
#include <stdint.h>

// Problem constants (fixed by setup_inputs)
#define S_LEN 2048
#define HID   1024
#define NHEAD 16
#define DHEAD 64
#define BATCH 2

// 0.125 (1/sqrt(DHEAD)) * log2(e): folded into Q so softmax runs in exp2 domain
#define QSCALE 0.18033688f
#define MASKNEG -14427.0f

typedef __bf16 bf16_t;
typedef __bf16 bf16x4 __attribute__((ext_vector_type(4)));
typedef __bf16 bf16x8 __attribute__((ext_vector_type(8)));
typedef float  f32x4  __attribute__((ext_vector_type(4)));

// NOTE (R5/R6/R8 lesson): never put __launch_bounds__ second arg or
// amdgpu_waves_per_eu on the MFMA kernels here. acc[] lives in AGPRs; any
// unified-budget cap starves the arch half and triggers a 200+ MB scratch
// spill storm (WRITE_SIZE blowup). Default allocation is spill-free.

// ---------------- async global->LDS (width 16) ----------------
__device__ __forceinline__ void gl_lds16(const bf16_t* g, bf16_t* l) {
  __builtin_amdgcn_global_load_lds((const __attribute__((address_space(1))) void*)g,
                                   (__attribute__((address_space(3))) void*)l,
                                   16, 0, 0);
}

// Stage TR x TC bf16 tile (row-major, ldg elements) into LDS with xor chunk
// swizzle: LDS slot (16B) index = r*CH + (c ^ (r & (CH-1))).
template<int TR, int TC>
__device__ __forceinline__ void stage_tile(const bf16_t* __restrict__ g, int ldg,
                                           bf16_t* lds, int wave, int lane) {
  constexpr int CH = TC / 8;            // 16B chunks per row
  constexpr int NINST = (TR * CH) / 64; // 1KB instructions
  #pragma unroll
  for (int i = wave; i < NINST; i += 4) {
    int slot = i * 64 + lane;
    int r  = slot / CH;
    int cs = slot & (CH - 1);
    int c  = cs ^ (r & (CH - 1));       // logical chunk living at swizzled slot
    gl_lds16(g + (size_t)r * ldg + c * 8, lds + i * 512);
  }
}

// Read one MFMA fragment (8 contiguous k-elements, 16B) from a swizzled tile.
template<int CH>
__device__ __forceinline__ bf16x8 frag_ld(const bf16_t* lds, int row, int kchunk) {
  int cs = kchunk ^ (row & (CH - 1));
  return *(const bf16x8*)(lds + (row * CH + cs) * 8);
}

// ---------------- fused prep: cvt3 + weight transpose + mask flags ---------
// Flattened 1D grid; the three roles are independent so they overlap on the
// machine instead of serializing across 3 launches.
//   blocks [0, 12288): fp32->bf16 convert of q,k,v (which = bx/4096)
//   blocks [12288, 13312): W[in][out] f32 -> WT[out][in] bf16 (4 weights)
//   blocks [13312, 13568): mask -> flags[b][qtile][rg][kt] (plain stores,
//     each block owns its rg slice -- no init/ordering needed)
__global__ __launch_bounds__(256) void prep(
    const float* __restrict__ q, const float* __restrict__ k, const float* __restrict__ v,
    const float* __restrict__ w0, const float* __restrict__ w1,
    const float* __restrict__ w2, const float* __restrict__ w3,
    const int* __restrict__ mask,
    bf16_t* __restrict__ qb, bf16_t* __restrict__ kb, bf16_t* __restrict__ vb,
    bf16_t* __restrict__ wt, int* __restrict__ flags) {
  __shared__ float t[64][65];
  __shared__ int oks[16];
  int bx = blockIdx.x;
  int tid = threadIdx.x;

  if (bx < 12288) {  // cvt role
    int which = bx >> 12;
    int chunk = bx & 4095;
    const float* src = which == 0 ? q : which == 1 ? k : v;
    bf16_t* dst = which == 0 ? qb : which == 1 ? kb : vb;
    size_t i = ((size_t)chunk * 256 + tid) * 4;
    float4 u = *(const float4*)(src + i);
    bf16x4 o = {(bf16_t)u.x, (bf16_t)u.y, (bf16_t)u.z, (bf16_t)u.w};
    *(bf16x4*)(dst + i) = o;
    return;
  }
  if (bx < 13312) {  // transpose role
    int tt = bx - 12288;
    int z = tt >> 8, y = (tt >> 4) & 15, x = tt & 15;
    const float* W = z == 0 ? w0 : z == 1 ? w1 : z == 2 ? w2 : w3;
    bf16_t* WT = wt + (size_t)z * HID * HID;
    int tx = tid & 63, ty = tid >> 6;
    int r0 = y * 64, c0 = x * 64;
    #pragma unroll
    for (int i = ty; i < 64; i += 4) t[i][tx] = W[(size_t)(r0 + i) * HID + c0 + tx];
    __syncthreads();
    #pragma unroll
    for (int i = ty; i < 64; i += 4) WT[(size_t)(c0 + i) * HID + r0 + tx] = (bf16_t)t[tx][i];
    return;
  }
  {  // mask role: 16 coalesced rows; a thread's 8 cols lie in one kt (tid>>4)
    int tt = bx - 13312;                 // 0..255
    int b = tt >> 7, rg = (tt >> 4) & 7, qtile = tt & 15;
    const int* base = mask + (size_t)b * S_LEN * S_LEN
                    + (size_t)(qtile * 128 + rg * 16) * S_LEN;
    int kt = tid >> 4;
    int ok = 1;
    #pragma unroll
    for (int r = 0; r < 16; ++r) {
      const int4* p = (const int4*)(base + (size_t)r * S_LEN + tid * 8);
      int4 a = p[0], c = p[1];
      ok &= (a.x != 0) & (a.y != 0) & (a.z != 0) & (a.w != 0) &
            (c.x != 0) & (c.y != 0) & (c.z != 0) & (c.w != 0);
    }
    if (tid < 16) oks[tid] = -1;
    __syncthreads();
    if (!ok) atomicAnd(&oks[kt], 0);
    __syncthreads();
    if (tid < 16) flags[((b * 16 + qtile) * 8 + rg) * 16 + tid] = oks[tid];
  }
}

// ---------------- fused QKV projection GEMM (gemm_bt, 128x128 tile) ----------
// bf16 A (pre-converted by prep). R4-proven structure, default reg allocation.
// mode 0: Qh[b][h][s][d] (pre-scaled by QSCALE), mode 1: Kh[b][h][s][d],
// mode 2: VhT[b][h][d][s] (operand-swapped MFMA -> C^T in regs -> coalesced)
__global__ __launch_bounds__(256) void qkv_gemm(
    const bf16_t* __restrict__ qb, const bf16_t* __restrict__ kb, const bf16_t* __restrict__ vb,
    const bf16_t* __restrict__ wT,
    const float* __restrict__ bq, const float* __restrict__ bk, const float* __restrict__ bv,
    bf16_t* __restrict__ Qh, bf16_t* __restrict__ Kh, bf16_t* __restrict__ VhT) {
  int mode = blockIdx.z;
  const bf16_t* A    = mode == 0 ? qb : mode == 1 ? kb : vb;
  const bf16_t* Bt   = wT + (size_t)mode * HID * HID;
  const float*  bias = mode == 0 ? bq : mode == 1 ? bk : bv;

  __shared__ __align__(16) bf16_t As[128 * 64];
  __shared__ __align__(16) bf16_t Bs[128 * 64];

  int tid = threadIdx.x, wave = tid >> 6, lane = tid & 63;
  int lane15 = lane & 15, quad = lane >> 4;
  int m0 = blockIdx.x * 128, n0 = blockIdx.y * 128;
  int wm = (wave >> 1) * 64, wn = (wave & 1) * 64;

  f32x4 zero4 = {0.f, 0.f, 0.f, 0.f};
  f32x4 acc[4][4];
  #pragma unroll
  for (int t = 0; t < 4; ++t)
    #pragma unroll
    for (int n = 0; n < 4; ++n) acc[t][n] = zero4;

  for (int k0 = 0; k0 < HID; k0 += 64) {
    stage_tile<128, 64>(A  + (size_t)m0 * HID + k0, HID, As, wave, lane);
    stage_tile<128, 64>(Bt + (size_t)n0 * HID + k0, HID, Bs, wave, lane);
    __syncthreads();
    #pragma unroll
    for (int kc = 0; kc < 2; ++kc) {
      bf16x8 af[4], bfr[4];
      #pragma unroll
      for (int t = 0; t < 4; ++t) af[t]  = frag_ld<8>(As, wm + t * 16 + lane15, kc * 4 + quad);
      #pragma unroll
      for (int n = 0; n < 4; ++n) bfr[n] = frag_ld<8>(Bs, wn + n * 16 + lane15, kc * 4 + quad);
      if (mode < 2) {
        #pragma unroll
        for (int t = 0; t < 4; ++t)
          #pragma unroll
          for (int n = 0; n < 4; ++n)
            acc[t][n] = __builtin_amdgcn_mfma_f32_16x16x32_bf16(af[t], bfr[n], acc[t][n], 0, 0, 0);
      } else {
        // swapped: acc[t][n] holds C^T tile: row=feature, col=token
        #pragma unroll
        for (int t = 0; t < 4; ++t)
          #pragma unroll
          for (int n = 0; n < 4; ++n)
            acc[t][n] = __builtin_amdgcn_mfma_f32_16x16x32_bf16(bfr[n], af[t], acc[t][n], 0, 0, 0);
      }
    }
    __syncthreads();
  }

  if (mode < 2) {
    float sc = (mode == 0) ? QSCALE : 1.0f;
    bf16_t* dst = (mode == 0 ? Qh : Kh);
    #pragma unroll
    for (int t = 0; t < 4; ++t) {
      #pragma unroll
      for (int n = 0; n < 4; ++n) {
        int col = n0 + wn + n * 16 + lane15;
        float bb = bias[col];
        #pragma unroll
        for (int i = 0; i < 4; ++i) {
          int row = m0 + wm + t * 16 + quad * 4 + i;
          bf16_t o = (bf16_t)((acc[t][n][i] + bb) * sc);
          int b = row >> 11, s = row & 2047;
          int h = col >> 6,  d = col & 63;
          dst[((size_t)(b * NHEAD + h) * S_LEN + s) * DHEAD + d] = o;
        }
      }
    }
  } else {
    // C^T layout: lane15 = token within tile t, quad*4+i = feature within tile n
    #pragma unroll
    for (int n = 0; n < 4; ++n) {
      int dbase = n0 + wn + n * 16 + quad * 4;
      float4 bb4 = *(const float4*)(bias + dbase);
      #pragma unroll
      for (int t = 0; t < 4; ++t) {
        int token = m0 + wm + t * 16 + lane15;
        int b = token >> 11, s = token & 2047;
        #pragma unroll
        for (int i = 0; i < 4; ++i) {
          int dg = dbase + i;
          int h = dg >> 6, d = dg & 63;
          float bb = i == 0 ? bb4.x : i == 1 ? bb4.y : i == 2 ? bb4.z : bb4.w;
          VhT[((size_t)(b * NHEAD + h) * DHEAD + d) * S_LEN + s] = (bf16_t)(acc[t][n][i] + bb);
        }
      }
    }
  }
}

// ---------------- flash attention (S^T, fixed-max, split-K over kt) --------
// grid: (16 q-tiles, B*NHEAD=32, 2 kt-halves) = 1024 blocks. block 256.
// Each block handles 8 of 16 kt tiles, emits UNNORMALIZED partial O^T (bf16)
// + l (fp32); fixed-max softmax => O = (O0+O1)/(l0+l1) exactly.
// LDS 40KB (Ks 16 + VTs 16 + Ps 8) -> 4 blocks/CU if VGPR <= ~128.
// DEFAULT register allocation (R5/R6/R8: any cap => spill storm).
__global__ __launch_bounds__(256) void attn_kernel(
    const bf16_t* __restrict__ Qh, const bf16_t* __restrict__ Kh, const bf16_t* __restrict__ VhT,
    const int* __restrict__ mask, const int* __restrict__ flags,
    bf16_t* __restrict__ OP, float* __restrict__ LP) {
  __shared__ __align__(16) bf16_t Ks[128 * 64];   // 16KB (also stages Q first)
  __shared__ __align__(16) bf16_t VTs[64 * 128];  // 16KB
  __shared__ __align__(16) bf16_t Ps[128 * 32];   // 8KB, CH=4 swizzle

  int tid = threadIdx.x, wave = tid >> 6, lane = tid & 63;
  int lane15 = lane & 15, quad = lane >> 4;
  int bh = blockIdx.y, b = bh >> 4;
  int qt = blockIdx.x;
  int half = blockIdx.z;
  int wrow = wave * 32;

  // stage the 128x64 Q tile into Ks; Q fragments live in registers
  stage_tile<128, 64>(Qh + ((size_t)bh * S_LEN + qt * 128) * DHEAD, DHEAD, Ks, wave, lane);
  __syncthreads();
  bf16x8 qa[2][2];  // [kc][nq] B-operand frags: row = q
  #pragma unroll
  for (int kc = 0; kc < 2; ++kc)
    #pragma unroll
    for (int nq = 0; nq < 2; ++nq)
      qa[kc][nq] = frag_ld<8>(Ks, wrow + nq * 16 + lane15, kc * 4 + quad);
  __syncthreads();  // all waves done reading Q before Ks is restaged

  f32x4 zero4 = {0.f, 0.f, 0.f, 0.f};
  f32x4 o_acc[2][4];  // [nq][mt] O^T tiles: row = d, col = q
  float l_acc[2] = {0.f, 0.f};
  #pragma unroll
  for (int nq = 0; nq < 2; ++nq)
    #pragma unroll
    for (int mt = 0; mt < 4; ++mt) o_acc[nq][mt] = zero4;

  for (int ktl = 0; ktl < 8; ++ktl) {
    int kt = half * 8 + ktl;
    stage_tile<128, 64>(Kh + ((size_t)bh * S_LEN + kt * 128) * DHEAD, DHEAD, Ks, wave, lane);
    stage_tile<64, 128>(VhT + (size_t)bh * DHEAD * S_LEN + kt * 128, S_LEN, VTs, wave, lane);
    __syncthreads();

    int fl = -1;  // AND of the 8 rowgroup flags (uniform scalar loads)
    #pragma unroll
    for (int rg = 0; rg < 8; ++rg) fl &= flags[((b * 16 + qt) * 8 + rg) * 16 + kt];
    bool masked = (fl == 0);

    #pragma unroll
    for (int qtr = 0; qtr < 4; ++qtr) {
      // S^T quarter: 32 c x 32 q per wave
      f32x4 sa[2][2];
      #pragma unroll
      for (int nq = 0; nq < 2; ++nq)
        #pragma unroll
        for (int mc = 0; mc < 2; ++mc) sa[nq][mc] = zero4;
      #pragma unroll
      for (int kc = 0; kc < 2; ++kc) {
        bf16x8 kf[2];
        #pragma unroll
        for (int mc = 0; mc < 2; ++mc)
          kf[mc] = frag_ld<8>(Ks, qtr * 32 + mc * 16 + lane15, kc * 4 + quad);
        #pragma unroll
        for (int nq = 0; nq < 2; ++nq)
          #pragma unroll
          for (int mc = 0; mc < 2; ++mc)
            sa[nq][mc] = __builtin_amdgcn_mfma_f32_16x16x32_bf16(kf[mc], qa[kc][nq], sa[nq][mc], 0, 0, 0);
      }

      if (masked) {
        #pragma unroll
        for (int nq = 0; nq < 2; ++nq)
          #pragma unroll
          for (int mc = 0; mc < 2; ++mc)
            #pragma unroll
            for (int i = 0; i < 4; ++i) {
              int q = qt * 128 + wrow + nq * 16 + lane15;
              int c = kt * 128 + qtr * 32 + mc * 16 + quad * 4 + i;
              if (mask[(size_t)b * S_LEN * S_LEN + (size_t)q * S_LEN + c] == 0)
                sa[nq][mc][i] = MASKNEG;
            }
      }

      // p = exp2(s); accumulate l in-lane; pack & write P quarter (CH=4)
      #pragma unroll
      for (int nq = 0; nq < 2; ++nq) {
        int q = wrow + nq * 16 + lane15;
        #pragma unroll
        for (int mc = 0; mc < 2; ++mc) {
          float e0 = exp2f(sa[nq][mc][0]), e1 = exp2f(sa[nq][mc][1]);
          float e2 = exp2f(sa[nq][mc][2]), e3 = exp2f(sa[nq][mc][3]);
          l_acc[nq] += (e0 + e1) + (e2 + e3);
          bf16x4 pk = {(bf16_t)e0, (bf16_t)e1, (bf16_t)e2, (bf16_t)e3};
          int chunk = mc * 2 + (quad >> 1);
          int slot = chunk ^ (q & 3);
          *(bf16x4*)(Ps + q * 32 + slot * 8 + (quad & 1) * 4) = pk;
        }
      }

      // O^T += V^T(quarter) P^T(quarter): K=32 -> one MFMA per (nq, mt)
      bf16x8 vf[4], pf[2];
      #pragma unroll
      for (int mt = 0; mt < 4; ++mt)
        vf[mt] = frag_ld<16>(VTs, mt * 16 + lane15, qtr * 4 + quad);
      #pragma unroll
      for (int nq = 0; nq < 2; ++nq)
        pf[nq] = frag_ld<4>(Ps, wrow + nq * 16 + lane15, quad);
      #pragma unroll
      for (int nq = 0; nq < 2; ++nq)
        #pragma unroll
        for (int mt = 0; mt < 4; ++mt)
          o_acc[nq][mt] = __builtin_amdgcn_mfma_f32_16x16x32_bf16(vf[mt], pf[nq], o_acc[nq][mt], 0, 0, 0);
    }
    __syncthreads();
  }

  // epilogue: finish l reduction across quads; store UNNORMALIZED partials
  #pragma unroll
  for (int nq = 0; nq < 2; ++nq) {
    float lv = l_acc[nq];
    lv += __shfl_xor(lv, 16);
    lv += __shfl_xor(lv, 32);
    int s = qt * 128 + wrow + nq * 16 + lane15;
    size_t obase = (size_t)(half * 32 + bh) * S_LEN + s;
    #pragma unroll
    for (int mt = 0; mt < 4; ++mt) {
      bf16x4 ov = {(bf16_t)o_acc[nq][mt][0], (bf16_t)o_acc[nq][mt][1],
                   (bf16_t)o_acc[nq][mt][2], (bf16_t)o_acc[nq][mt][3]};
      *(bf16x4*)(OP + obase * 64 + mt * 16 + quad * 4) = ov;
    }
    if (quad == 0) LP[obase] = lv;
  }
}

// ---------------- combine split-K partials -> Obuf (bf16) ----------------
__global__ __launch_bounds__(256) void attn_combine(
    const bf16_t* __restrict__ OP, const float* __restrict__ LP,
    bf16_t* __restrict__ O) {
  int bh = blockIdx.y, b = bh >> 4, h = bh & 15;
  int s = blockIdx.x * 32 + (threadIdx.x >> 3);
  int d0 = (threadIdx.x & 7) * 8;
  size_t i0 = (size_t)bh * S_LEN + s;
  size_t i1 = (size_t)(32 + bh) * S_LEN + s;
  bf16x8 a = *(const bf16x8*)(OP + i0 * 64 + d0);
  bf16x8 c = *(const bf16x8*)(OP + i1 * 64 + d0);
  float inv = 1.0f / (LP[i0] + LP[i1]);
  bf16x8 o;
  #pragma unroll
  for (int j = 0; j < 8; ++j)
    o[j] = (bf16_t)(((float)a[j] + (float)c[j]) * inv);
  *(bf16x8*)(O + ((size_t)b * S_LEN + s) * HID + h * DHEAD + d0) = o;
}

// ---------------- output projection GEMM (fp32 out) ----------------
__global__ __launch_bounds__(256) void oproj_gemm(
    const bf16_t* __restrict__ A, const bf16_t* __restrict__ Bt,
    const float* __restrict__ bias, float* __restrict__ out) {
  __shared__ __align__(16) bf16_t As[128 * 64];
  __shared__ __align__(16) bf16_t Bs[128 * 64];

  int tid = threadIdx.x, wave = tid >> 6, lane = tid & 63;
  int lane15 = lane & 15, quad = lane >> 4;
  int m0 = blockIdx.x * 128, n0 = blockIdx.y * 128;
  int wm = (wave >> 1) * 64, wn = (wave & 1) * 64;

  f32x4 zero4 = {0.f, 0.f, 0.f, 0.f};
  f32x4 acc[4][4];
  #pragma unroll
  for (int t = 0; t < 4; ++t)
    #pragma unroll
    for (int n = 0; n < 4; ++n) acc[t][n] = zero4;

  for (int k0 = 0; k0 < HID; k0 += 64) {
    stage_tile<128, 64>(A  + (size_t)m0 * HID + k0, HID, As, wave, lane);
    stage_tile<128, 64>(Bt + (size_t)n0 * HID + k0, HID, Bs, wave, lane);
    __syncthreads();
    #pragma unroll
    for (int kc = 0; kc < 2; ++kc) {
      bf16x8 af[4], bfr[4];
      #pragma unroll
      for (int t = 0; t < 4; ++t) af[t]  = frag_ld<8>(As, wm + t * 16 + lane15, kc * 4 + quad);
      #pragma unroll
      for (int n = 0; n < 4; ++n) bfr[n] = frag_ld<8>(Bs, wn + n * 16 + lane15, kc * 4 + quad);
      #pragma unroll
      for (int t = 0; t < 4; ++t)
        #pragma unroll
        for (int n = 0; n < 4; ++n)
          acc[t][n] = __builtin_amdgcn_mfma_f32_16x16x32_bf16(af[t], bfr[n], acc[t][n], 0, 0, 0);
    }
    __syncthreads();
  }

  #pragma unroll
  for (int t = 0; t < 4; ++t) {
    #pragma unroll
    for (int n = 0; n < 4; ++n) {
      int col = n0 + wn + n * 16 + lane15;
      float bb = bias[col];
      #pragma unroll
      for (int i = 0; i < 4; ++i) {
        int row = m0 + wm + t * 16 + quad * 4 + i;
        out[(size_t)row * HID + col] = acc[t][n][i] + bb;
      }
    }
  }
}

// ---------------- launcher ----------------
extern "C" void kernel_launch(void* const* d_in, const int* in_sizes, int n_in,
                              void* d_out, int out_size, void* d_ws, size_t ws_size,
                              hipStream_t stream) {
  (void)in_sizes; (void)n_in; (void)out_size; (void)ws_size;
  const float* q  = (const float*)d_in[0];
  const float* k  = (const float*)d_in[1];
  const float* v  = (const float*)d_in[2];
  const int*  mask = (const int*)d_in[3];
  const float* wq = (const float*)d_in[4];
  const float* bq = (const float*)d_in[5];
  const float* wk = (const float*)d_in[6];
  const float* bk = (const float*)d_in[7];
  const float* wv = (const float*)d_in[8];
  const float* bv = (const float*)d_in[9];
  const float* wo = (const float*)d_in[10];
  const float* bo = (const float*)d_in[11];

  char* ws = (char*)d_ws;
  bf16_t* wT    = (bf16_t*)(ws);                 // 8 MB: wqT,wkT,wvT,woT (bf16)
  bf16_t* Qh    = (bf16_t*)(ws + (8u  << 20));   // 8 MB [B,NH,S,D] (pre-scaled)
  bf16_t* Kh    = (bf16_t*)(ws + (16u << 20));   // 8 MB [B,NH,S,D]
  bf16_t* VhT   = (bf16_t*)(ws + (24u << 20));   // 8 MB [B,NH,D,S]
  bf16_t* qb    = (bf16_t*)(ws + (32u << 20));   // 8 MB bf16 q
  bf16_t* kb    = (bf16_t*)(ws + (40u << 20));   // 8 MB bf16 k
  bf16_t* vb    = (bf16_t*)(ws + (48u << 20));   // 8 MB bf16 v
  int* flags    = (int*)(ws + (56u << 20));      // 4 KB [B][16 qt][8 rg][16 kt]
  // consumed-slot reuse (qkv reads qb/kb/vb before attn writes partials):
  bf16_t* OP    = (bf16_t*)(ws + (32u << 20));   // 16 MB partial O^T [2][32][2048][64]
  float*  LPx   = (float*)(ws + (48u << 20));    // 512 KB partial l [2][32][2048]
  bf16_t* Obuf  = Qh;  // attn consumed Qh before combine writes Obuf

  prep<<<13568, 256, 0, stream>>>(q, k, v, wq, wk, wv, wo, mask, qb, kb, vb, wT, flags);
  qkv_gemm<<<dim3(32, 8, 3), 256, 0, stream>>>(qb, kb, vb, wT, bq, bk, bv, Qh, Kh, VhT);
  attn_kernel<<<dim3(16, 32, 2), 256, 0, stream>>>(Qh, Kh, VhT, mask, flags, OP, LPx);
  attn_combine<<<dim3(64, 32), 256, 0, stream>>>(OP, LPx, Obuf);
  oproj_gemm<<<dim3(32, 8), 256, 0, stream>>>(Obuf, wT + (size_t)3 * HID * HID, bo, (float*)d_out);
}